// Round 1
// baseline (112.141 us; speedup 1.0000x reference)
//
#include <hip/hip_runtime.h>

namespace {
constexpr int B = 16, C = 19, H = 512, W = 512;
constexpr int BLOCK_W = 256;          // threads per block, one image column each
constexpr int H_CHUNK = 128;          // rows per block
constexpr int NWB = W / BLOCK_W;      // 2
constexpr int NHC = H / H_CHUNK;      // 4
constexpr int TOTAL_BLOCKS = B * C * NWB * NHC;  // 2432
constexpr float SCALE = 1.0f / (float)((long long)B * H * W);  // mean over B,H,W
}

__global__ void zero_out_kernel(float* out) { *out = 0.0f; }

__global__ __launch_bounds__(BLOCK_W) void edge_loss_kernel(
    const float* __restrict__ X,   // [B,C,H,W] f32
    const int*   __restrict__ T,   // [B,H,W] int32 labels
    float* __restrict__ out)
{
    // c fastest-varying: 19 consecutive blocks share one target tile (L2 reuse)
    int bid = (int)blockIdx.x;
    const int c  = bid % C;   bid /= C;
    const int wb = bid % NWB; bid /= NWB;
    const int hc = bid % NHC; bid /= NHC;
    const int b  = bid;

    const int w  = wb * BLOCK_W + (int)threadIdx.x;
    const int h0 = hc * H_CHUNK;

    const float* __restrict__ Xs = X + (((size_t)b * C + c) * H) * (size_t)W;
    const int*   __restrict__ Ts = T + ((size_t)b * H) * (size_t)W;

    // clamped neighbor columns + 0/1 border masks (branchless)
    const bool wl = (w > 0), wr = (w < W - 1);
    const int wm = wl ? (w - 1) : 0;
    const int wp = wr ? (w + 1) : (W - 1);
    const float fl = wl ? 1.0f : 0.0f;
    const float fr = wr ? 1.0f : 0.0f;

    // rolling 3x3 windows: input values x__, one-hot mask m__ (row, col)
    float x00,x01,x02, x10,x11,x12, x20,x21,x22;
    float m00,m01,m02, m10,m11,m12, m20,m21,m22;

    const float* xrow = Xs + (size_t)h0 * W;
    const int*   trow = Ts + (size_t)h0 * W;

    if (h0 > 0) {   // preload row h0-1 (wave-uniform branch)
        const float* xp = xrow - W;
        const int*   tp = trow - W;
        x00 = xp[wm] * fl; x01 = xp[w]; x02 = xp[wp] * fr;
        const int t0 = tp[wm], t1 = tp[w], t2 = tp[wp];
        m00 = (t0 == c) ? fl : 0.0f;
        m01 = (t1 == c) ? 1.0f : 0.0f;
        m02 = (t2 == c) ? fr : 0.0f;
    } else {
        x00 = x01 = x02 = 0.0f; m00 = m01 = m02 = 0.0f;
    }
    // preload row h0
    {
        x10 = xrow[wm] * fl; x11 = xrow[w]; x12 = xrow[wp] * fr;
        const int t0 = trow[wm], t1 = trow[w], t2 = trow[wp];
        m10 = (t0 == c) ? fl : 0.0f;
        m11 = (t1 == c) ? 1.0f : 0.0f;
        m12 = (t2 == c) ? fr : 0.0f;
    }

    const float* xn = xrow + W;   // row h+1 pointer
    const int*   tn = trow + W;

    float acc = 0.0f;
    #pragma unroll 4
    for (int h = h0; h < h0 + H_CHUNK; ++h) {
        if (h + 1 < H) {          // wave-uniform
            x20 = xn[wm] * fl; x21 = xn[w]; x22 = xn[wp] * fr;
            const int t0 = tn[wm], t1 = tn[w], t2 = tn[wp];
            m20 = (t0 == c) ? fl : 0.0f;
            m21 = (t1 == c) ? 1.0f : 0.0f;
            m22 = (t2 == c) ? fr : 0.0f;
        } else {
            x20 = x21 = x22 = 0.0f; m20 = m21 = m22 = 0.0f;
        }
        xn += W; tn += W;

        // Sobel (cross-correlation): gx = right-col minus left-col, [1,2,1] vertical
        float gx = (x02 - x00) + 2.0f*(x12 - x10) + (x22 - x20);
        float gy = (x20 + 2.0f*x21 + x22) - (x00 + 2.0f*x01 + x02);
        float ein = fabsf(gx) + fabsf(gy);

        float hx = (m02 - m00) + 2.0f*(m12 - m10) + (m22 - m20);
        float hy = (m20 + 2.0f*m21 + m22) - (m00 + 2.0f*m01 + m02);
        float etg = fabsf(hx) + fabsf(hy);

        const float d = ein - etg;
        acc = fmaf(d, d, acc);

        // shift window down one row
        x00 = x10; x01 = x11; x02 = x12;
        x10 = x20; x11 = x21; x12 = x22;
        m00 = m10; m01 = m11; m02 = m12;
        m10 = m20; m11 = m21; m12 = m22;
    }

    // wave reduce (64 lanes)
    #pragma unroll
    for (int off = 32; off > 0; off >>= 1)
        acc += __shfl_down(acc, off, 64);

    __shared__ float wsum[BLOCK_W / 64];
    const int lane = (int)threadIdx.x & 63;
    const int wid  = (int)threadIdx.x >> 6;
    if (lane == 0) wsum[wid] = acc;
    __syncthreads();
    if (threadIdx.x == 0) {
        const float s = wsum[0] + wsum[1] + wsum[2] + wsum[3];
        atomicAdd(out, s * SCALE);
    }
}

extern "C" void kernel_launch(void* const* d_in, const int* in_sizes, int n_in,
                              void* d_out, int out_size, void* d_ws, size_t ws_size,
                              hipStream_t stream) {
    (void)in_sizes; (void)n_in; (void)d_ws; (void)ws_size; (void)out_size;
    const float* X = (const float*)d_in[0];
    const int*   T = (const int*)d_in[1];
    float* out = (float*)d_out;

    zero_out_kernel<<<1, 1, 0, stream>>>(out);
    edge_loss_kernel<<<TOTAL_BLOCKS, BLOCK_W, 0, stream>>>(X, T, out);
}